// Round 4
// baseline (551.488 us; speedup 1.0000x reference)
//
#include <hip/hip_runtime.h>
#include <stdint.h>

// ---- Problem constants ----
// B=8192, IN=2048, OUT=2048, G=4.  K_total = 4096 (x-half then h-half).
// gates[b][g][o] = sum_k x[b][k]*Wi[g][k][o] + bi[g][o] + sum_k h[b][k]*Wh[g][k][o] + bh[g][o]
// next_c = sig(g1)*prev_c + sig(g0)*sig(g2);  next_h = sig(g3) + tanh(next_c)
// d_out = [next_h (8192*2048 f32)] ++ [next_c (8192*2048 f32)]

#define SZ_ELEMS 16777216
#define HALF_OUT 16777216

typedef __attribute__((ext_vector_type(8))) short bf16x8;
typedef __attribute__((ext_vector_type(4))) float f32x4;
typedef __attribute__((ext_vector_type(8))) unsigned short u16x8;

__device__ __forceinline__ unsigned short f2bf(float f) {
  unsigned int u = __float_as_uint(f);
  u += 0x7FFFu + ((u >> 16) & 1u);
  return (unsigned short)(u >> 16);
}

__device__ __forceinline__ void async16(const void* g, void* l) {
  __builtin_amdgcn_global_load_lds(
      (const __attribute__((address_space(1))) void*)g,
      (__attribute__((address_space(3))) void*)l, 16, 0, 0);
}

__device__ __forceinline__ float sigm(float x) { return 1.f / (1.f + __expf(-x)); }

// ---------------- f32 -> bf16 elementwise convert ----------------
__global__ void cvt_bf16_kernel(const float* __restrict__ src,
                                unsigned short* __restrict__ dst, int n4) {
  int i = blockIdx.x * blockDim.x + threadIdx.x;
  int stride = gridDim.x * blockDim.x;
  for (; i < n4; i += stride) {
    float4 v = reinterpret_cast<const float4*>(src)[i];
    ushort4 o;
    o.x = f2bf(v.x); o.y = f2bf(v.y); o.z = f2bf(v.z); o.w = f2bf(v.w);
    reinterpret_cast<ushort4*>(dst)[i] = o;
  }
}

// ---------------- W [g][k][o] f32  ->  Wt [g][o][k] bf16 ----------------
__global__ void transpose_w_kernel(const float* __restrict__ Wi, const float* __restrict__ Wh,
                                   unsigned short* __restrict__ Wit, unsigned short* __restrict__ Wht) {
  __shared__ float tile[64][65];
  const int tk = blockIdx.x, to = blockIdx.y, gz = blockIdx.z;
  const float* W = (gz < 4 ? Wi : Wh) + (size_t)(gz & 3) * 4194304;
  unsigned short* Wt = (gz < 4 ? Wit : Wht) + (size_t)(gz & 3) * 4194304;
  const int t = threadIdx.x;
  const int o = t & 63, kr = t >> 6;
#pragma unroll
  for (int p = 0; p < 16; ++p) {
    int k = p * 4 + kr;
    tile[k][o] = W[(size_t)(tk * 64 + k) * 2048 + to * 64 + o];
  }
  __syncthreads();
#pragma unroll
  for (int p = 0; p < 2; ++p) {
    int idx = p * 256 + t;
    int orow = idx >> 3, k0 = (idx & 7) * 8;
    u16x8 v;
#pragma unroll
    for (int i = 0; i < 8; ++i) v[i] = f2bf(tile[k0 + i][orow]);
    *reinterpret_cast<u16x8*>(&Wt[(size_t)(to * 64 + orow) * 2048 + tk * 64 + k0]) = v;
  }
}

// ---------------- fused GEMM (4 gates) + LSTM epilogue, 8-phase schedule ----------------
// BM=256 batch x [4 gates x 64 o] (=256 "N"), BK=64, 512 threads (8 waves: 2M x 4N).
// Wave tile 128(M) x 64(N). acc[8][4] f32x4 = 128 VGPR.
// LDS: 2 buffers x (A 256x64 + B 256x64 bf16) = 128 KiB (1 block/CU). XOR swizzle.
// Block->tile mapping (round-4 fix): each XCD owns a bm STRIP, not a bo strip:
//   xcd = flat&7, pos = flat>>3; bm = xcd*4 + (pos>>5); bo = pos&31.
// Resident set per XCD = ~32 blocks, SAME bm (A-panel 2MB -> XCD L2-resident),
// sweeping all 32 bo; B total 64MB -> L3-resident, HBM-fetched ~once overall.
// Iteration = 2 K-tiles, 8 phases; each phase stages one 16KB half-tile.
// vmcnt(6) only at phases 4 & 8 (3 half-tiles = 6 loads in flight, never drained).
#define FENCE asm volatile("" ::: "memory")
#define BARRIER do { FENCE; __builtin_amdgcn_s_barrier(); FENCE; } while (0)
#define LGKM0 asm volatile("s_waitcnt lgkmcnt(0)" ::: "memory")
#define LGKM8 asm volatile("s_waitcnt lgkmcnt(8)" ::: "memory")
#define VMC6  asm volatile("s_waitcnt vmcnt(6)" ::: "memory")
#define VMC0  asm volatile("s_waitcnt vmcnt(0)" ::: "memory")

__global__ __launch_bounds__(512, 2) void lstm_gemm_kernel(
    const unsigned short* __restrict__ xb, const unsigned short* __restrict__ hb,
    const unsigned short* __restrict__ wit, const unsigned short* __restrict__ wht,
    const float* __restrict__ bi, const float* __restrict__ bh,
    const float* __restrict__ prev_c, float* __restrict__ out) {
  __shared__ char lds[131072];

  const int tid = threadIdx.x;
  const int wave = tid >> 6, lane = tid & 63;
  const int wm = wave >> 2, wn = wave & 3;
  // XCD-aware mapping: bm strip per XCD (A-panel in XCD L2; B sweeps L3-resident 64MB)
  const int flat = blockIdx.x;
  const int xcd = flat & 7, pos = flat >> 3;
  const int bm = xcd * 4 + (pos >> 5);   // 0..31
  const int bo = pos & 31;               // 0..31

  // --- fragment ds_read offsets ---
  const int kwin = (lane >> 4) << 4;
  const int fswz = (lane & 7) << 4;
  int aro[8], bro[4];
#pragma unroll
  for (int mf = 0; mf < 8; ++mf) aro[mf] = (wm * 128 + mf * 16 + (lane & 15)) * 128;
#pragma unroll
  for (int nf = 0; nf < 4; ++nf) bro[nf] = 32768 + (nf * 64 + wn * 16 + (lane & 15)) * 128;

  // --- staging offsets (pre-swizzled global src, linear LDS dest; rule #21) ---
  const int L0 = tid * 16;
  int agoff[2][2], bgoff[2][2];
#pragma unroll
  for (int h = 0; h < 2; ++h)
#pragma unroll
    for (int j = 0; j < 2; ++j) {
      int L = j * 8192 + L0;
      int row = h * 128 + (L >> 7);                // 0..255
      int c = (L & 127) ^ ((row & 7) << 4);
      agoff[h][j] = row * 4096 + c;                // A row = batch row
      int g = row >> 6, orow = row & 63;           // B row = g*64 + orow
      bgoff[h][j] = g * 8388608 + orow * 4096 + c;
    }
  const char* pxa = (const char*)xb + (size_t)bm * 1048576;
  const char* pha = (const char*)hb + (size_t)bm * 1048576;
  const char* pwi = (const char*)wit + (size_t)bo * 262144;
  const char* pwh = (const char*)wht + (size_t)bo * 262144;

  auto stageA = [&](int t, int h, int buf) {
    const char* base = (t < 32) ? (pxa + t * 128) : (pha + (t - 32) * 128);
    char* d = lds + buf * 65536 + h * 16384 + L0;
    async16(base + agoff[h][0], d);
    async16(base + agoff[h][1], d + 8192);
  };
  auto stageB = [&](int t, int h, int buf) {
    const char* base = (t < 32) ? (pwi + t * 128) : (pwh + (t - 32) * 128);
    char* d = lds + buf * 65536 + 32768 + h * 16384 + L0;
    async16(base + bgoff[h][0], d);
    async16(base + bgoff[h][1], d + 8192);
  };

  f32x4 acc[8][4];
  const f32x4 zero = {0.f, 0.f, 0.f, 0.f};
#pragma unroll
  for (int mf = 0; mf < 8; ++mf)
#pragma unroll
    for (int nf = 0; nf < 4; ++nf) acc[mf][nf] = zero;

  bf16x8 afr[4][2];   // one A quadrant-half (reused lo->hi)
  bf16x8 bfr[4][2];   // both B halves live

  auto loadA = [&](int buf, int mh) {
    const char* l = lds + buf * 65536;
#pragma unroll
    for (int m = 0; m < 4; ++m)
#pragma unroll
      for (int ks = 0; ks < 2; ++ks)
        afr[m][ks] = *(const bf16x8*)(l + aro[mh * 4 + m] + ((ks * 64 + kwin) ^ fswz));
  };
  auto loadB = [&](int buf, int nh) {
    const char* l = lds + buf * 65536;
#pragma unroll
    for (int n = 0; n < 2; ++n)
#pragma unroll
      for (int ks = 0; ks < 2; ++ks)
        bfr[nh * 2 + n][ks] = *(const bf16x8*)(l + bro[nh * 2 + n] + ((ks * 64 + kwin) ^ fswz));
  };
  auto MF16 = [&](int mh, int nh) {
    __builtin_amdgcn_s_setprio(1);
#pragma unroll
    for (int ks = 0; ks < 2; ++ks)
#pragma unroll
      for (int n = 0; n < 2; ++n)
#pragma unroll
        for (int m = 0; m < 4; ++m)
          acc[mh * 4 + m][nh * 2 + n] = __builtin_amdgcn_mfma_f32_16x16x32_bf16(
              afr[m][ks], bfr[nh * 2 + n][ks], acc[mh * 4 + m][nh * 2 + n], 0, 0, 0);
    __builtin_amdgcn_s_setprio(0);
  };

  // --- prologue: t0 all 4 halves -> buf0; t1 {B0,B1,A0} -> buf1 ---
  stageB(0, 0, 0); stageB(0, 1, 0); stageA(0, 0, 0); stageA(0, 1, 0);
  stageB(1, 0, 1); stageB(1, 1, 1); stageA(1, 0, 1);
  VMC6;          // t0's 8 loads landed; t1's 6 still in flight
  BARRIER;

  // --- main loop: iterations 0..30, tiles t0=2i (buf0), t1=2i+1 (buf1) ---
  for (int i = 0; i < 31; ++i) {
    const int t1 = 2 * i + 1, t2 = 2 * i + 2, t3 = 2 * i + 3;
    // P1: Q00 of t0
    loadA(0, 0); loadB(0, 0); stageA(t1, 1, 1); LGKM8; BARRIER; LGKM0; MF16(0, 0); BARRIER;
    // P2: Q01
    loadB(0, 1); stageB(t2, 0, 0); BARRIER; LGKM0; MF16(0, 1); BARRIER;
    // P3: Q10
    loadA(0, 1); stageB(t2, 1, 0); BARRIER; LGKM0; MF16(1, 0); BARRIER;
    // P4: Q11 (regs only)
    stageA(t2, 0, 0); BARRIER; MF16(1, 1); VMC6; BARRIER;   // all of t1 landed
    // P5: Q00 of t1
    loadA(1, 0); loadB(1, 0); stageA(t2, 1, 0); LGKM8; BARRIER; LGKM0; MF16(0, 0); BARRIER;
    // P6: Q01
    loadB(1, 1); stageB(t3, 0, 1); BARRIER; LGKM0; MF16(0, 1); BARRIER;
    // P7: Q10
    loadA(1, 1); stageB(t3, 1, 1); BARRIER; LGKM0; MF16(1, 0); BARRIER;
    // P8: Q11
    stageA(t3, 0, 1); BARRIER; MF16(1, 1); VMC6; BARRIER;   // all of t2 landed
  }

  // --- epilogue iteration: tiles 62 (buf0), 63 (buf1); only stage = t63A1 ---
  loadA(0, 0); loadB(0, 0); stageA(63, 1, 1); LGKM8; BARRIER; LGKM0; MF16(0, 0); BARRIER;
  loadB(0, 1); BARRIER; LGKM0; MF16(0, 1); BARRIER;
  loadA(0, 1); BARRIER; LGKM0; MF16(1, 0); BARRIER;
  BARRIER; MF16(1, 1); VMC0; BARRIER;                        // t63 fully landed
  loadA(1, 0); loadB(1, 0); LGKM8; BARRIER; LGKM0; MF16(0, 0); BARRIER;
  loadB(1, 1); BARRIER; LGKM0; MF16(0, 1); BARRIER;
  loadA(1, 1); BARRIER; LGKM0; MF16(1, 0); BARRIER;
  MF16(1, 1);

  // --- LSTM cell epilogue (lane-local; C/D: col=lane&15, row=(lane>>4)*4+reg) ---
  const int col = lane & 15, rg = lane >> 4;
  const int o = bo * 64 + wn * 16 + col;
  float bs[4];
#pragma unroll
  for (int g = 0; g < 4; ++g) bs[g] = bi[g * 2048 + o] + bh[g * 2048 + o];
#pragma unroll
  for (int mf = 0; mf < 8; ++mf) {
    int bbase = bm * 256 + wm * 128 + mf * 16 + rg * 4;
#pragma unroll
    for (int r = 0; r < 4; ++r) {
      int b = bbase + r;
      float gi = sigm(acc[mf][0][r] + bs[0]);
      float gf = sigm(acc[mf][1][r] + bs[1]);
      float g2 = sigm(acc[mf][2][r] + bs[2]);
      float go = sigm(acc[mf][3][r] + bs[3]);
      float c = prev_c[(size_t)b * 2048 + o];
      float nc = gf * c + gi * g2;
      float e = __expf(2.f * nc);
      float nh = go + (e - 1.f) / (e + 1.f);   // faithful: out_gate + tanh(next_c)
      out[(size_t)b * 2048 + o] = nh;
      out[(size_t)HALF_OUT + (size_t)b * 2048 + o] = nc;
    }
  }
}

extern "C" void kernel_launch(void* const* d_in, const int* in_sizes, int n_in,
                              void* d_out, int out_size, void* d_ws, size_t ws_size,
                              hipStream_t stream) {
  const float* x  = (const float*)d_in[0];
  const float* ph = (const float*)d_in[1];
  const float* pc = (const float*)d_in[2];
  const float* Wi = (const float*)d_in[3];
  const float* Wh = (const float*)d_in[4];
  const float* bi = (const float*)d_in[5];
  const float* bh = (const float*)d_in[6];
  float* out = (float*)d_out;

  if (ws_size < (size_t)4 * SZ_ELEMS * sizeof(unsigned short)) return;
  unsigned short* xb  = (unsigned short*)d_ws;
  unsigned short* hb  = xb + SZ_ELEMS;
  unsigned short* wit = hb + SZ_ELEMS;
  unsigned short* wht = wit + SZ_ELEMS;

  cvt_bf16_kernel<<<2048, 256, 0, stream>>>(x, xb, 4194304);
  cvt_bf16_kernel<<<2048, 256, 0, stream>>>(ph, hb, 4194304);
  transpose_w_kernel<<<dim3(32, 32, 8), 256, 0, stream>>>(Wi, Wh, wit, wht);
  lstm_gemm_kernel<<<dim3(1024), 512, 0, stream>>>(xb, hb, wit, wht, bi, bh, pc, out);
}

// Round 5
// 531.014 us; speedup vs baseline: 1.0386x; 1.0386x over previous
//
#include <hip/hip_runtime.h>
#include <stdint.h>

// ---- Problem constants ----
// B=8192, IN=2048, OUT=2048, G=4.  K_total = 4096 (x-half then h-half).
// gates[b][g][o] = sum_k x[b][k]*Wi[g][k][o] + bi[g][o] + sum_k h[b][k]*Wh[g][k][o] + bh[g][o]
// next_c = sig(g1)*prev_c + sig(g0)*sig(g2);  next_h = sig(g3) + tanh(next_c)
// d_out = [next_h (8192*2048 f32)] ++ [next_c (8192*2048 f32)]

#define SZ_ELEMS 16777216
#define HALF_OUT 16777216

typedef __attribute__((ext_vector_type(8))) short bf16x8;
typedef __attribute__((ext_vector_type(4))) float f32x4;
typedef __attribute__((ext_vector_type(8))) unsigned short u16x8;

__device__ __forceinline__ unsigned short f2bf(float f) {
  unsigned int u = __float_as_uint(f);
  u += 0x7FFFu + ((u >> 16) & 1u);
  return (unsigned short)(u >> 16);
}

__device__ __forceinline__ void async16(const void* g, void* l) {
  __builtin_amdgcn_global_load_lds(
      (const __attribute__((address_space(1))) void*)g,
      (__attribute__((address_space(3))) void*)l, 16, 0, 0);
}

__device__ __forceinline__ float sigm(float x) { return 1.f / (1.f + __expf(-x)); }

// ---------------- f32 -> bf16 elementwise convert ----------------
__global__ void cvt_bf16_kernel(const float* __restrict__ src,
                                unsigned short* __restrict__ dst, int n4) {
  int i = blockIdx.x * blockDim.x + threadIdx.x;
  int stride = gridDim.x * blockDim.x;
  for (; i < n4; i += stride) {
    float4 v = reinterpret_cast<const float4*>(src)[i];
    ushort4 o;
    o.x = f2bf(v.x); o.y = f2bf(v.y); o.z = f2bf(v.z); o.w = f2bf(v.w);
    reinterpret_cast<ushort4*>(dst)[i] = o;
  }
}

// ---------------- W [g][k][o] f32  ->  Wt [g][o][k] bf16 ----------------
__global__ void transpose_w_kernel(const float* __restrict__ Wi, const float* __restrict__ Wh,
                                   unsigned short* __restrict__ Wit, unsigned short* __restrict__ Wht) {
  __shared__ float tile[64][65];
  const int tk = blockIdx.x, to = blockIdx.y, gz = blockIdx.z;
  const float* W = (gz < 4 ? Wi : Wh) + (size_t)(gz & 3) * 4194304;
  unsigned short* Wt = (gz < 4 ? Wit : Wht) + (size_t)(gz & 3) * 4194304;
  const int t = threadIdx.x;
  const int o = t & 63, kr = t >> 6;
#pragma unroll
  for (int p = 0; p < 16; ++p) {
    int k = p * 4 + kr;
    tile[k][o] = W[(size_t)(tk * 64 + k) * 2048 + to * 64 + o];
  }
  __syncthreads();
#pragma unroll
  for (int p = 0; p < 2; ++p) {
    int idx = p * 256 + t;
    int orow = idx >> 3, k0 = (idx & 7) * 8;
    u16x8 v;
#pragma unroll
    for (int i = 0; i < 8; ++i) v[i] = f2bf(tile[k0 + i][orow]);
    *reinterpret_cast<u16x8*>(&Wt[(size_t)(to * 64 + orow) * 2048 + tk * 64 + k0]) = v;
  }
}

// ---------------- fused GEMM (4 gates) + LSTM epilogue, 8-phase schedule ----------------
// BM=256 batch x [4 gates x 64 o] (=256 "N"), BK=64, 512 threads (8 waves: 2M x 4N).
// Wave tile 128(M) x 64(N). acc[8][4] f32x4 = 128 VGPR.
// LDS: 2 buffers x (A 256x64 + B 256x64 bf16) = 128 KiB (1 block/CU). XOR swizzle.
// Grid mapping (round-5): NATURAL 2D grid, bm = blockIdx.x (inner-fast), bo = blockIdx.y.
//   Evidence: r2 (this mapping, 2-phase) fetched 427 MB; both 1D remaps (r3/r4, 8-phase)
//   fetched 1115 MB identically -> instantaneous machine-wide working set governs L3
//   residency, and natural x-fast order keeps it to {all A + ~8 B panels} < L3.
// Iteration = 2 K-tiles, 8 phases; each phase stages one 16KB half-tile.
// vmcnt(6) only at phases 4 & 8 (3 half-tiles = 6 loads in flight, never drained).
#define FENCE asm volatile("" ::: "memory")
#define BARRIER do { FENCE; __builtin_amdgcn_s_barrier(); FENCE; } while (0)
#define LGKM0 asm volatile("s_waitcnt lgkmcnt(0)" ::: "memory")
#define LGKM8 asm volatile("s_waitcnt lgkmcnt(8)" ::: "memory")
#define VMC6  asm volatile("s_waitcnt vmcnt(6)" ::: "memory")
#define VMC0  asm volatile("s_waitcnt vmcnt(0)" ::: "memory")

__global__ __launch_bounds__(512, 2) void lstm_gemm_kernel(
    const unsigned short* __restrict__ xb, const unsigned short* __restrict__ hb,
    const unsigned short* __restrict__ wit, const unsigned short* __restrict__ wht,
    const float* __restrict__ bi, const float* __restrict__ bh,
    const float* __restrict__ prev_c, float* __restrict__ out) {
  __shared__ char lds[131072];

  const int tid = threadIdx.x;
  const int wave = tid >> 6, lane = tid & 63;
  const int wm = wave >> 2, wn = wave & 3;
  const int bm = blockIdx.x;   // 0..31 (batch tile, inner-fast in dispatch order)
  const int bo = blockIdx.y;   // 0..31 (out-col tile)

  // --- fragment ds_read offsets ---
  const int kwin = (lane >> 4) << 4;
  const int fswz = (lane & 7) << 4;
  int aro[8], bro[4];
#pragma unroll
  for (int mf = 0; mf < 8; ++mf) aro[mf] = (wm * 128 + mf * 16 + (lane & 15)) * 128;
#pragma unroll
  for (int nf = 0; nf < 4; ++nf) bro[nf] = 32768 + (nf * 64 + wn * 16 + (lane & 15)) * 128;

  // --- staging offsets (pre-swizzled global src, linear LDS dest; rule #21) ---
  const int L0 = tid * 16;
  int agoff[2][2], bgoff[2][2];
#pragma unroll
  for (int h = 0; h < 2; ++h)
#pragma unroll
    for (int j = 0; j < 2; ++j) {
      int L = j * 8192 + L0;
      int row = h * 128 + (L >> 7);                // 0..255
      int c = (L & 127) ^ ((row & 7) << 4);
      agoff[h][j] = row * 4096 + c;                // A row = batch row
      int g = row >> 6, orow = row & 63;           // B row = g*64 + orow
      bgoff[h][j] = g * 8388608 + orow * 4096 + c;
    }
  const char* pxa = (const char*)xb + (size_t)bm * 1048576;
  const char* pha = (const char*)hb + (size_t)bm * 1048576;
  const char* pwi = (const char*)wit + (size_t)bo * 262144;
  const char* pwh = (const char*)wht + (size_t)bo * 262144;

  auto stageA = [&](int t, int h, int buf) {
    const char* base = (t < 32) ? (pxa + t * 128) : (pha + (t - 32) * 128);
    char* d = lds + buf * 65536 + h * 16384 + L0;
    async16(base + agoff[h][0], d);
    async16(base + agoff[h][1], d + 8192);
  };
  auto stageB = [&](int t, int h, int buf) {
    const char* base = (t < 32) ? (pwi + t * 128) : (pwh + (t - 32) * 128);
    char* d = lds + buf * 65536 + 32768 + h * 16384 + L0;
    async16(base + bgoff[h][0], d);
    async16(base + bgoff[h][1], d + 8192);
  };

  f32x4 acc[8][4];
  const f32x4 zero = {0.f, 0.f, 0.f, 0.f};
#pragma unroll
  for (int mf = 0; mf < 8; ++mf)
#pragma unroll
    for (int nf = 0; nf < 4; ++nf) acc[mf][nf] = zero;

  bf16x8 afr[4][2];   // one A quadrant-half (reused lo->hi)
  bf16x8 bfr[4][2];   // both B halves live

  auto loadA = [&](int buf, int mh) {
    const char* l = lds + buf * 65536;
#pragma unroll
    for (int m = 0; m < 4; ++m)
#pragma unroll
      for (int ks = 0; ks < 2; ++ks)
        afr[m][ks] = *(const bf16x8*)(l + aro[mh * 4 + m] + ((ks * 64 + kwin) ^ fswz));
  };
  auto loadB = [&](int buf, int nh) {
    const char* l = lds + buf * 65536;
#pragma unroll
    for (int n = 0; n < 2; ++n)
#pragma unroll
      for (int ks = 0; ks < 2; ++ks)
        bfr[nh * 2 + n][ks] = *(const bf16x8*)(l + bro[nh * 2 + n] + ((ks * 64 + kwin) ^ fswz));
  };
  auto MF16 = [&](int mh, int nh) {
    __builtin_amdgcn_s_setprio(1);
#pragma unroll
    for (int ks = 0; ks < 2; ++ks)
#pragma unroll
      for (int n = 0; n < 2; ++n)
#pragma unroll
        for (int m = 0; m < 4; ++m)
          acc[mh * 4 + m][nh * 2 + n] = __builtin_amdgcn_mfma_f32_16x16x32_bf16(
              afr[m][ks], bfr[nh * 2 + n][ks], acc[mh * 4 + m][nh * 2 + n], 0, 0, 0);
    __builtin_amdgcn_s_setprio(0);
  };

  // --- prologue: t0 all 4 halves -> buf0; t1 {B0,B1,A0} -> buf1 ---
  stageB(0, 0, 0); stageB(0, 1, 0); stageA(0, 0, 0); stageA(0, 1, 0);
  stageB(1, 0, 1); stageB(1, 1, 1); stageA(1, 0, 1);
  VMC6;          // t0's 8 loads landed; t1's 6 still in flight
  BARRIER;

  // --- main loop: iterations 0..30, tiles t0=2i (buf0), t1=2i+1 (buf1) ---
  for (int i = 0; i < 31; ++i) {
    const int t1 = 2 * i + 1, t2 = 2 * i + 2, t3 = 2 * i + 3;
    // P1: Q00 of t0
    loadA(0, 0); loadB(0, 0); stageA(t1, 1, 1); LGKM8; BARRIER; LGKM0; MF16(0, 0); BARRIER;
    // P2: Q01
    loadB(0, 1); stageB(t2, 0, 0); BARRIER; LGKM0; MF16(0, 1); BARRIER;
    // P3: Q10
    loadA(0, 1); stageB(t2, 1, 0); BARRIER; LGKM0; MF16(1, 0); BARRIER;
    // P4: Q11 (regs only)
    stageA(t2, 0, 0); BARRIER; MF16(1, 1); VMC6; BARRIER;   // all of t1 landed
    // P5: Q00 of t1
    loadA(1, 0); loadB(1, 0); stageA(t2, 1, 0); LGKM8; BARRIER; LGKM0; MF16(0, 0); BARRIER;
    // P6: Q01
    loadB(1, 1); stageB(t3, 0, 1); BARRIER; LGKM0; MF16(0, 1); BARRIER;
    // P7: Q10
    loadA(1, 1); stageB(t3, 1, 1); BARRIER; LGKM0; MF16(1, 0); BARRIER;
    // P8: Q11
    stageA(t3, 0, 1); BARRIER; MF16(1, 1); VMC6; BARRIER;   // all of t2 landed
  }

  // --- epilogue iteration: tiles 62 (buf0), 63 (buf1); only stage = t63A1 ---
  loadA(0, 0); loadB(0, 0); stageA(63, 1, 1); LGKM8; BARRIER; LGKM0; MF16(0, 0); BARRIER;
  loadB(0, 1); BARRIER; LGKM0; MF16(0, 1); BARRIER;
  loadA(0, 1); BARRIER; LGKM0; MF16(1, 0); BARRIER;
  BARRIER; MF16(1, 1); VMC0; BARRIER;                        // t63 fully landed
  loadA(1, 0); loadB(1, 0); LGKM8; BARRIER; LGKM0; MF16(0, 0); BARRIER;
  loadB(1, 1); BARRIER; LGKM0; MF16(0, 1); BARRIER;
  loadA(1, 1); BARRIER; LGKM0; MF16(1, 0); BARRIER;
  MF16(1, 1);

  // --- LSTM cell epilogue (lane-local; C/D: col=lane&15, row=(lane>>4)*4+reg) ---
  const int col = lane & 15, rg = lane >> 4;
  const int o = bo * 64 + wn * 16 + col;
  float bs[4];
#pragma unroll
  for (int g = 0; g < 4; ++g) bs[g] = bi[g * 2048 + o] + bh[g * 2048 + o];
#pragma unroll
  for (int mf = 0; mf < 8; ++mf) {
    int bbase = bm * 256 + wm * 128 + mf * 16 + rg * 4;
#pragma unroll
    for (int r = 0; r < 4; ++r) {
      int b = bbase + r;
      float gi = sigm(acc[mf][0][r] + bs[0]);
      float gf = sigm(acc[mf][1][r] + bs[1]);
      float g2 = sigm(acc[mf][2][r] + bs[2]);
      float go = sigm(acc[mf][3][r] + bs[3]);
      float c = prev_c[(size_t)b * 2048 + o];
      float nc = gf * c + gi * g2;
      float e = __expf(2.f * nc);
      float nh = go + (e - 1.f) / (e + 1.f);   // faithful: out_gate + tanh(next_c)
      out[(size_t)b * 2048 + o] = nh;
      out[(size_t)HALF_OUT + (size_t)b * 2048 + o] = nc;
    }
  }
}

extern "C" void kernel_launch(void* const* d_in, const int* in_sizes, int n_in,
                              void* d_out, int out_size, void* d_ws, size_t ws_size,
                              hipStream_t stream) {
  const float* x  = (const float*)d_in[0];
  const float* ph = (const float*)d_in[1];
  const float* pc = (const float*)d_in[2];
  const float* Wi = (const float*)d_in[3];
  const float* Wh = (const float*)d_in[4];
  const float* bi = (const float*)d_in[5];
  const float* bh = (const float*)d_in[6];
  float* out = (float*)d_out;

  if (ws_size < (size_t)4 * SZ_ELEMS * sizeof(unsigned short)) return;
  unsigned short* xb  = (unsigned short*)d_ws;
  unsigned short* hb  = xb + SZ_ELEMS;
  unsigned short* wit = hb + SZ_ELEMS;
  unsigned short* wht = wit + SZ_ELEMS;

  cvt_bf16_kernel<<<2048, 256, 0, stream>>>(x, xb, 4194304);
  cvt_bf16_kernel<<<2048, 256, 0, stream>>>(ph, hb, 4194304);
  transpose_w_kernel<<<dim3(32, 32, 8), 256, 0, stream>>>(Wi, Wh, wit, wht);
  lstm_gemm_kernel<<<dim3(32, 32), 512, 0, stream>>>(xb, hb, wit, wht, bi, bh, pc, out);
}